// Round 16
// baseline (319.774 us; speedup 1.0000x reference)
//
#include <hip/hip_runtime.h>
#include <hip/hip_bf16.h>

#define NN 8192
#define DIN 512
#define DH 256
#define DO_ 128
#define NCLS 8
#define NE 262144

typedef __attribute__((ext_vector_type(8))) short bf16x8;
typedef __attribute__((ext_vector_type(4))) float f32x4;
typedef __attribute__((ext_vector_type(4))) unsigned short u16x4;
typedef __attribute__((ext_vector_type(8))) unsigned short u16x8;

__device__ __forceinline__ unsigned short f2bf(float x) {
    unsigned int u = __float_as_uint(x);
    return (unsigned short)((u + 0x7FFFu + ((u >> 16) & 1u)) >> 16);
}
__device__ __forceinline__ float bf2f(unsigned short h) {
    return __uint_as_float((unsigned int)h << 16);
}

#define GLDS(gp, lp) __builtin_amdgcn_global_load_lds( \
    (const __attribute__((address_space(1))) void*)(gp), \
    (__attribute__((address_space(3))) void*)(lp), 16, 0, 0)

__device__ __forceinline__ void cvt8_store(unsigned short* dst, float4 a, float4 b) {
    u16x8 o;
    o[0] = f2bf(a.x); o[1] = f2bf(a.y); o[2] = f2bf(a.z); o[3] = f2bf(a.w);
    o[4] = f2bf(b.x); o[5] = f2bf(b.y); o[6] = f2bf(b.z); o[7] = f2bf(b.w);
    *(u16x8*)dst = o;
}
__device__ __forceinline__ void cvt8_split_store(unsigned short* dH, unsigned short* dL, float4 a, float4 b) {
    u16x8 oh, ol;
    unsigned short h;
    h = f2bf(a.x); oh[0] = h; ol[0] = f2bf(a.x - bf2f(h));
    h = f2bf(a.y); oh[1] = h; ol[1] = f2bf(a.y - bf2f(h));
    h = f2bf(a.z); oh[2] = h; ol[2] = f2bf(a.z - bf2f(h));
    h = f2bf(a.w); oh[3] = h; ol[3] = f2bf(a.w - bf2f(h));
    h = f2bf(b.x); oh[4] = h; ol[4] = f2bf(b.x - bf2f(h));
    h = f2bf(b.y); oh[5] = h; ol[5] = f2bf(b.y - bf2f(h));
    h = f2bf(b.z); oh[6] = h; ol[6] = f2bf(b.z - bf2f(h));
    h = f2bf(b.w); oh[7] = h; ol[7] = f2bf(b.w - bf2f(h));
    *(u16x8*)dH = oh;
    *(u16x8*)dL = ol;
}

// u8 fixed-point encode of PPMI (x in [0,1/8192)): u = round(x * 8192 * 255)
#define U8SCALE 2088960.0f
__device__ __forceinline__ unsigned int pack4_u8(float4 v) {
    unsigned int b0 = (unsigned int)(v.x * U8SCALE + 0.5f);
    unsigned int b1 = (unsigned int)(v.y * U8SCALE + 0.5f);
    unsigned int b2 = (unsigned int)(v.z * U8SCALE + 0.5f);
    unsigned int b3 = (unsigned int)(v.w * U8SCALE + 0.5f);
    return b0 | (b1 << 8) | (b2 << 16) | (b3 << 24);
}
__device__ __forceinline__ float4 dec4_u8(unsigned int d) {
    const float s = 1.0f / 255.0f;
    return make_float4((float)(d & 255u) * s, (float)((d >> 8) & 255u) * s,
                       (float)((d >> 16) & 255u) * s, (float)(d >> 24) * s);
}

// ================= compute bodies =================

// ---- LS1: h0 = feats(f32, inline hi/lo split) @ w1l_eff^T, 3-term split MFMA ----
__device__ void dev_ls1(int bx, int by, const float* __restrict__ A,
                        const unsigned short* __restrict__ Bh, const unsigned short* __restrict__ Bl,
                        float* __restrict__ C) {
    __shared__ unsigned short AsH[128 * 32];
    __shared__ unsigned short AsL[128 * 32];
    __shared__ unsigned short BsH[128 * 32];
    __shared__ unsigned short BsL[128 * 32];
    const int t = threadIdx.x;
    const int w = t >> 6;
    const int l = t & 63;
    const int wr = (w >> 1) * 64;
    const int wc = (w & 1) * 64;
    const long row0 = (long)bx * 128;
    const long col0 = (long)by * 128;
    const int K = DIN;
    const int nk = DIN >> 5;

    f32x4 acc[4][4];
#pragma unroll
    for (int mi = 0; mi < 4; ++mi)
#pragma unroll
        for (int ni = 0; ni < 4; ++ni) { f32x4 z = {0.f,0.f,0.f,0.f}; acc[mi][ni] = z; }

    const int ar = t >> 1;
    const int akh = (t & 1) << 4;
    const float* Abase = A + (row0 + ar) * K + akh;
    const int aoff = ar * 32 + akh;
    const int srow = (w << 4) + (l >> 2);
    const int skk  = (l & 3) << 3;
    const unsigned short* BhB = Bh + (col0 + srow) * K + skk;
    const unsigned short* BlB = Bl + (col0 + srow) * K + skk;
    unsigned short* BsHW = &BsH[w << 9];
    unsigned short* BsLW = &BsL[w << 9];

    for (int kt = 0; kt < nk; ++kt) {
        const long ko = (long)kt << 5;
        __syncthreads();
        float4 fa0 = *(const float4*)(Abase + ko);
        float4 fa1 = *(const float4*)(Abase + ko + 4);
        float4 fa2 = *(const float4*)(Abase + ko + 8);
        float4 fa3 = *(const float4*)(Abase + ko + 12);
        GLDS(BhB + ko,                BsHW);
        GLDS(BhB + (long)64 * K + ko, BsHW + 2048);
        GLDS(BlB + ko,                BsLW);
        GLDS(BlB + (long)64 * K + ko, BsLW + 2048);
        cvt8_split_store(&AsH[aoff],     &AsL[aoff],     fa0, fa1);
        cvt8_split_store(&AsH[aoff + 8], &AsL[aoff + 8], fa2, fa3);
        __syncthreads();

        const int ro  = (l & 15);
        const int kof = (l >> 4) << 3;
        bf16x8 ah[4], al[4], bh[4], bl[4];
#pragma unroll
        for (int mi = 0; mi < 4; ++mi) {
            ah[mi] = *(const bf16x8*)&AsH[(wr + mi * 16 + ro) * 32 + kof];
            al[mi] = *(const bf16x8*)&AsL[(wr + mi * 16 + ro) * 32 + kof];
        }
#pragma unroll
        for (int ni = 0; ni < 4; ++ni) {
            bh[ni] = *(const bf16x8*)&BsH[(wc + ni * 16 + ro) * 32 + kof];
            bl[ni] = *(const bf16x8*)&BsL[(wc + ni * 16 + ro) * 32 + kof];
        }
#pragma unroll
        for (int mi = 0; mi < 4; ++mi)
#pragma unroll
            for (int ni = 0; ni < 4; ++ni) {
                acc[mi][ni] = __builtin_amdgcn_mfma_f32_16x16x32_bf16(ah[mi], bl[ni], acc[mi][ni], 0, 0, 0);
                acc[mi][ni] = __builtin_amdgcn_mfma_f32_16x16x32_bf16(al[mi], bh[ni], acc[mi][ni], 0, 0, 0);
                acc[mi][ni] = __builtin_amdgcn_mfma_f32_16x16x32_bf16(ah[mi], bh[ni], acc[mi][ni], 0, 0, 0);
            }
    }
#pragma unroll
    for (int mi = 0; mi < 4; ++mi)
#pragma unroll
        for (int ni = 0; ni < 4; ++ni) {
            const long col = col0 + wc + ni * 16 + (l & 15);
            const long rbase = row0 + wr + mi * 16 + ((l >> 4) << 2);
            f32x4 v = acc[mi][ni];
#pragma unroll
            for (int j = 0; j < 4; ++j) C[(rbase + j) * DH + col] = v[j];
        }
}

// ---- LS2: split-bf16 3-term GEMM, A bf16 hi/lo from global ----
__device__ void dev_gemm_split(int bx, int by,
                               const unsigned short* __restrict__ Ah, const unsigned short* __restrict__ Al,
                               const unsigned short* __restrict__ Bh, const unsigned short* __restrict__ Bl,
                               float* __restrict__ C, int M, int N, int K) {
    __shared__ unsigned short AsH2[128 * 32];
    __shared__ unsigned short AsL2[128 * 32];
    __shared__ unsigned short BsH2[128 * 32];
    __shared__ unsigned short BsL2[128 * 32];
    const int t = threadIdx.x;
    const int w = t >> 6;
    const int l = t & 63;
    const int wr = (w >> 1) * 64;
    const int wc = (w & 1) * 64;
    const long row0 = (long)bx * 128;
    const long col0 = (long)by * 128;
    const int nk = K >> 5;

    f32x4 acc[4][4];
#pragma unroll
    for (int mi = 0; mi < 4; ++mi)
#pragma unroll
        for (int ni = 0; ni < 4; ++ni) { f32x4 z = {0.f,0.f,0.f,0.f}; acc[mi][ni] = z; }

    const int srow = (w << 4) + (l >> 2);
    const int skk  = (l & 3) << 3;
    const long aoff = row0 * K + skk;
    const long boff = col0 * K + skk;
    unsigned short* AsHW = &AsH2[w << 9];
    unsigned short* AsLW = &AsL2[w << 9];
    unsigned short* BsHW = &BsH2[w << 9];
    unsigned short* BsLW = &BsL2[w << 9];

    for (int kt = 0; kt < nk; ++kt) {
        const long ko = (long)kt << 5;
        __syncthreads();
        GLDS(Ah + aoff + (long)srow * K + ko,        AsHW);
        GLDS(Ah + aoff + (long)(srow + 64) * K + ko, AsHW + 2048);
        GLDS(Al + aoff + (long)srow * K + ko,        AsLW);
        GLDS(Al + aoff + (long)(srow + 64) * K + ko, AsLW + 2048);
        GLDS(Bh + boff + (long)srow * K + ko,        BsHW);
        GLDS(Bh + boff + (long)(srow + 64) * K + ko, BsHW + 2048);
        GLDS(Bl + boff + (long)srow * K + ko,        BsLW);
        GLDS(Bl + boff + (long)(srow + 64) * K + ko, BsLW + 2048);
        __syncthreads();

        const int ro  = (l & 15);
        const int kof = (l >> 4) << 3;
        bf16x8 ah[4], al[4], bh[4], bl[4];
#pragma unroll
        for (int mi = 0; mi < 4; ++mi) {
            ah[mi] = *(const bf16x8*)&AsH2[(wr + mi * 16 + ro) * 32 + kof];
            al[mi] = *(const bf16x8*)&AsL2[(wr + mi * 16 + ro) * 32 + kof];
        }
#pragma unroll
        for (int ni = 0; ni < 4; ++ni) {
            bh[ni] = *(const bf16x8*)&BsH2[(wc + ni * 16 + ro) * 32 + kof];
            bl[ni] = *(const bf16x8*)&BsL2[(wc + ni * 16 + ro) * 32 + kof];
        }
#pragma unroll
        for (int mi = 0; mi < 4; ++mi)
#pragma unroll
            for (int ni = 0; ni < 4; ++ni) {
                acc[mi][ni] = __builtin_amdgcn_mfma_f32_16x16x32_bf16(ah[mi], bl[ni], acc[mi][ni], 0, 0, 0);
                acc[mi][ni] = __builtin_amdgcn_mfma_f32_16x16x32_bf16(al[mi], bh[ni], acc[mi][ni], 0, 0, 0);
                acc[mi][ni] = __builtin_amdgcn_mfma_f32_16x16x32_bf16(ah[mi], bh[ni], acc[mi][ni], 0, 0, 0);
            }
    }
#pragma unroll
    for (int mi = 0; mi < 4; ++mi)
#pragma unroll
        for (int ni = 0; ni < 4; ++ni) {
            const long col = col0 + wc + ni * 16 + (l & 15);
            const long rbase = row0 + wr + mi * 16 + ((l >> 4) << 2);
            f32x4 v = acc[mi][ni];
#pragma unroll
            for (int j = 0; j < 4; ++j) C[(rbase + j) * N + col] = v[j];
        }
}

// ---- GB1: g0t = (feats(f32->bf16 hi, inline) @ w1g_eff)^T ----
__device__ void dev_gb1(int bx, int by, const float* __restrict__ A,
                        const unsigned short* __restrict__ B, unsigned short* __restrict__ C) {
    __shared__ unsigned short AsG[128 * 32];
    __shared__ unsigned short BsG[128 * 32];
    const int t = threadIdx.x;
    const int w = t >> 6;
    const int l = t & 63;
    const int wr = (w >> 1) * 64;
    const int wc = (w & 1) * 64;
    const long row0 = (long)bx * 128;
    const long col0 = (long)by * 128;
    const int K = DIN;
    const int nk = DIN >> 5;

    f32x4 acc[4][4];
#pragma unroll
    for (int mi = 0; mi < 4; ++mi)
#pragma unroll
        for (int ni = 0; ni < 4; ++ni) { f32x4 z = {0.f,0.f,0.f,0.f}; acc[mi][ni] = z; }

    const int ar = t >> 1;
    const int akh = (t & 1) << 4;
    const float* Abase = A + (row0 + ar) * K + akh;
    const int aoff = ar * 32 + akh;
    const int srow = (w << 4) + (l >> 2);
    const int skk  = (l & 3) << 3;
    const unsigned short* Bbase = B + (col0 + srow) * K + skk;
    unsigned short* BsW = &BsG[w << 9];

    for (int kt = 0; kt < nk; ++kt) {
        const long ko = (long)kt << 5;
        __syncthreads();
        float4 fa0 = *(const float4*)(Abase + ko);
        float4 fa1 = *(const float4*)(Abase + ko + 4);
        float4 fa2 = *(const float4*)(Abase + ko + 8);
        float4 fa3 = *(const float4*)(Abase + ko + 12);
        GLDS(Bbase + ko,                BsW);
        GLDS(Bbase + (long)64 * K + ko, BsW + 2048);
        cvt8_store(&AsG[aoff],     fa0, fa1);
        cvt8_store(&AsG[aoff + 8], fa2, fa3);
        __syncthreads();

        const int ro  = (l & 15);
        const int kof = (l >> 4) << 3;
        bf16x8 a[4], b[4];
#pragma unroll
        for (int mi = 0; mi < 4; ++mi)
            a[mi] = *(const bf16x8*)&AsG[(wr + mi * 16 + ro) * 32 + kof];
#pragma unroll
        for (int ni = 0; ni < 4; ++ni)
            b[ni] = *(const bf16x8*)&BsG[(wc + ni * 16 + ro) * 32 + kof];
#pragma unroll
        for (int mi = 0; mi < 4; ++mi)
#pragma unroll
            for (int ni = 0; ni < 4; ++ni)
                acc[mi][ni] = __builtin_amdgcn_mfma_f32_16x16x32_bf16(a[mi], b[ni], acc[mi][ni], 0, 0, 0);
    }
#pragma unroll
    for (int mi = 0; mi < 4; ++mi)
#pragma unroll
        for (int ni = 0; ni < 4; ++ni) {
            const long col = col0 + wc + ni * 16 + (l & 15);
            const long rbase = row0 + wr + mi * 16 + ((l >> 4) << 2);
            f32x4 v = acc[mi][ni];
            u16x4 o;
            o.x = f2bf(v[0]); o.y = f2bf(v[1]); o.z = f2bf(v[2]); o.w = f2bf(v[3]);
            *(u16x4*)(C + col * NN + rbase) = o;
        }
}

// ---- GB2: single-bf16 GEMM, bf16 [N,M] transposed out ----
__device__ void dev_gemm_b1(int bx, int by,
                            const unsigned short* __restrict__ A, const unsigned short* __restrict__ B,
                            unsigned short* __restrict__ C, int M, int N, int K) {
    __shared__ unsigned short As1[128 * 32];
    __shared__ unsigned short Bs1[128 * 32];
    const int t = threadIdx.x;
    const int w = t >> 6;
    const int l = t & 63;
    const int wr = (w >> 1) * 64;
    const int wc = (w & 1) * 64;
    const long row0 = (long)bx * 128;
    const long col0 = (long)by * 128;
    const int nk = K >> 5;

    f32x4 acc[4][4];
#pragma unroll
    for (int mi = 0; mi < 4; ++mi)
#pragma unroll
        for (int ni = 0; ni < 4; ++ni) { f32x4 z = {0.f,0.f,0.f,0.f}; acc[mi][ni] = z; }

    const int srow = (w << 4) + (l >> 2);
    const int skk  = (l & 3) << 3;
    const unsigned short* Abase = A + row0 * K + skk;
    const unsigned short* Bbase = B + col0 * K + skk;
    unsigned short* AsW = &As1[w << 9];
    unsigned short* BsW = &Bs1[w << 9];

    for (int kt = 0; kt < nk; ++kt) {
        const long ko = (long)kt << 5;
        __syncthreads();
        GLDS(Abase + (long)srow * K + ko,        AsW);
        GLDS(Abase + (long)(srow + 64) * K + ko, AsW + 2048);
        GLDS(Bbase + (long)srow * K + ko,        BsW);
        GLDS(Bbase + (long)(srow + 64) * K + ko, BsW + 2048);
        __syncthreads();

        const int ro  = (l & 15);
        const int kof = (l >> 4) << 3;
        bf16x8 a[4], b[4];
#pragma unroll
        for (int mi = 0; mi < 4; ++mi)
            a[mi] = *(const bf16x8*)&As1[(wr + mi * 16 + ro) * 32 + kof];
#pragma unroll
        for (int ni = 0; ni < 4; ++ni)
            b[ni] = *(const bf16x8*)&Bs1[(wc + ni * 16 + ro) * 32 + kof];
#pragma unroll
        for (int mi = 0; mi < 4; ++mi)
#pragma unroll
            for (int ni = 0; ni < 4; ++ni)
                acc[mi][ni] = __builtin_amdgcn_mfma_f32_16x16x32_bf16(a[mi], b[ni], acc[mi][ni], 0, 0, 0);
    }
#pragma unroll
    for (int mi = 0; mi < 4; ++mi)
#pragma unroll
        for (int ni = 0; ni < 4; ++ni) {
            const long col = col0 + wc + ni * 16 + (l & 15);
            const long rbase = row0 + wr + mi * 16 + ((l >> 4) << 2);
            f32x4 v = acc[mi][ni];
            u16x4 o;
            o.x = f2bf(v[0]); o.y = f2bf(v[1]); o.z = f2bf(v[2]); o.w = f2bf(v[3]);
            *(u16x4*)(C + col * M + rbase) = o;
        }
}

// ---- PPMI GEMM 1 (512 thr, BM=128 BN=256, BK=64, z=8): u8 A, half the barriers ----
__device__ void dev_ppmi1(int bx, int z, const unsigned char* __restrict__ A8,
                          const unsigned short* __restrict__ B, unsigned short* __restrict__ C) {
    __shared__ unsigned short AsP[128 * 64];   // 16 KB
    __shared__ unsigned short BsP[256 * 64];   // 32 KB
    const int t = threadIdx.x;
    const int w = t >> 6;
    const int l = t & 63;
    const int wr = (w >> 2) * 64;
    const int wc = (w & 3) * 64;
    const long row0 = (long)bx * 128;
    const long kbeg = (long)z * (NN / 8);
    const int nk = (NN / 8) >> 6;   // 16
    const int K = NN;

    f32x4 acc[4][4];
#pragma unroll
    for (int mi = 0; mi < 4; ++mi)
#pragma unroll
        for (int ni = 0; ni < 4; ++ni) { f32x4 zz = {0.f,0.f,0.f,0.f}; acc[mi][ni] = zz; }

    // A: ar = t>>2 (128 rows), 16 u8 cols/thread (one uint4)
    const int ar = t >> 2;
    const int acq = (t & 3) << 4;
    const unsigned char* Abase = A8 + (row0 + ar) * (long)K + kbeg + acq;
    unsigned short* AsW = &AsP[ar * 64 + acq];
    // B: wave w covers rows w*32+(l>>3), chunk (l&7); 4 calls step rows by 8.
    // LDS dest linear: wave base + l*16B matches [row][64] layout.
    const int brow = (w << 5) + (l >> 3);
    const int bck  = (l & 7) << 3;
    const unsigned short* Bbase = B + (long)brow * K + kbeg + bck;
    unsigned short* BsW = &BsP[(w << 5) * 64];

    uint4 pa = *(const uint4*)(Abase);
    for (int kt = 0; kt < nk; ++kt) {
        const long ko = (long)kt << 6;
        __syncthreads();
        GLDS(Bbase + ko,                BsW);
        GLDS(Bbase + (long)8  * K + ko, BsW + 8 * 64);
        GLDS(Bbase + (long)16 * K + ko, BsW + 16 * 64);
        GLDS(Bbase + (long)24 * K + ko, BsW + 24 * 64);
        float4 g0 = dec4_u8(pa.x);
        float4 g1 = dec4_u8(pa.y);
        float4 g2v = dec4_u8(pa.z);
        float4 g3v = dec4_u8(pa.w);
        cvt8_store(AsW,     g0, g1);
        cvt8_store(AsW + 8, g2v, g3v);
        uint4 pn = pa;
        if (kt + 1 < nk) pn = *(const uint4*)(Abase + ko + 64);
        __syncthreads();

        const int ro  = (l & 15);
        const int kof = (l >> 4) << 3;
#pragma unroll
        for (int kk = 0; kk < 2; ++kk) {
            bf16x8 a[4], b[4];
#pragma unroll
            for (int mi = 0; mi < 4; ++mi)
                a[mi] = *(const bf16x8*)&AsP[(wr + mi * 16 + ro) * 64 + kk * 32 + kof];
#pragma unroll
            for (int ni = 0; ni < 4; ++ni)
                b[ni] = *(const bf16x8*)&BsP[(wc + ni * 16 + ro) * 64 + kk * 32 + kof];
#pragma unroll
            for (int mi = 0; mi < 4; ++mi)
#pragma unroll
                for (int ni = 0; ni < 4; ++ni)
                    acc[mi][ni] = __builtin_amdgcn_mfma_f32_16x16x32_bf16(a[mi], b[ni], acc[mi][ni], 0, 0, 0);
        }
        pa = pn;
    }

    unsigned short* Cp = C + (long)z * NN * DH;
#pragma unroll
    for (int mi = 0; mi < 4; ++mi)
#pragma unroll
        for (int ni = 0; ni < 4; ++ni) {
            const long col = wc + ni * 16 + (l & 15);
            const long rbase = row0 + wr + mi * 16 + ((l >> 4) << 2);
            f32x4 v = acc[mi][ni];
#pragma unroll
            for (int j = 0; j < 4; ++j) Cp[(rbase + j) * DH + col] = f2bf(v[j]);
        }
}

// ---- PPMI GEMM 2 (256 thr, BM=128 BN=128, BK=64, z=8): u8 A, half the barriers ----
__device__ void dev_ppmi2(int bx, int z, const unsigned char* __restrict__ A8,
                          const unsigned short* __restrict__ B, unsigned short* __restrict__ C) {
    __shared__ unsigned short AsQ[128 * 64];   // 16 KB
    __shared__ unsigned short BsQ[128 * 64];   // 16 KB
    const int t = threadIdx.x;
    const int w = t >> 6;
    const int l = t & 63;
    const int wr = (w >> 1) * 64;
    const int wc = (w & 1) * 64;
    const long row0 = (long)bx * 128;
    const long kbeg = (long)z * (NN / 8);
    const int nk = (NN / 8) >> 6;   // 16
    const int K = NN;

    f32x4 acc[4][4];
#pragma unroll
    for (int mi = 0; mi < 4; ++mi)
#pragma unroll
        for (int ni = 0; ni < 4; ++ni) { f32x4 zz = {0.f,0.f,0.f,0.f}; acc[mi][ni] = zz; }

    // A: ar = t>>1 (128 rows), 32 u8 cols/thread (two uint4)
    const int ar = t >> 1;
    const int acq = (t & 1) << 5;
    const unsigned char* Abase = A8 + (row0 + ar) * (long)K + kbeg + acq;
    unsigned short* AsW = &AsQ[ar * 64 + acq];
    // B: wave w covers rows w*8+(l>>3), chunk (l&7); 4 calls step rows by 32.
    const int brow = (w << 3) + (l >> 3);
    const int bck  = (l & 7) << 3;
    const unsigned short* Bbase = B + (long)brow * K + kbeg + bck;
    unsigned short* BsW = &BsQ[(w << 3) * 64];

    uint4 pa = *(const uint4*)(Abase);
    uint4 pb = *(const uint4*)(Abase + 16);
    for (int kt = 0; kt < nk; ++kt) {
        const long ko = (long)kt << 6;
        __syncthreads();
        GLDS(Bbase + ko,                BsW);
        GLDS(Bbase + (long)32 * K + ko, BsW + 32 * 64);
        GLDS(Bbase + (long)64 * K + ko, BsW + 64 * 64);
        GLDS(Bbase + (long)96 * K + ko, BsW + 96 * 64);
        float4 g0 = dec4_u8(pa.x);
        float4 g1 = dec4_u8(pa.y);
        float4 g2v = dec4_u8(pa.z);
        float4 g3v = dec4_u8(pa.w);
        float4 h0v = dec4_u8(pb.x);
        float4 h1v = dec4_u8(pb.y);
        float4 h2v = dec4_u8(pb.z);
        float4 h3v = dec4_u8(pb.w);
        cvt8_store(AsW,      g0, g1);
        cvt8_store(AsW + 8,  g2v, g3v);
        cvt8_store(AsW + 16, h0v, h1v);
        cvt8_store(AsW + 24, h2v, h3v);
        uint4 pan = pa, pbn = pb;
        if (kt + 1 < nk) {
            pan = *(const uint4*)(Abase + ko + 64);
            pbn = *(const uint4*)(Abase + ko + 80);
        }
        __syncthreads();

        const int ro  = (l & 15);
        const int kof = (l >> 4) << 3;
#pragma unroll
        for (int kk = 0; kk < 2; ++kk) {
            bf16x8 a[4], b[4];
#pragma unroll
            for (int mi = 0; mi < 4; ++mi)
                a[mi] = *(const bf16x8*)&AsQ[(wr + mi * 16 + ro) * 64 + kk * 32 + kof];
#pragma unroll
            for (int ni = 0; ni < 4; ++ni)
                b[ni] = *(const bf16x8*)&BsQ[(wc + ni * 16 + ro) * 64 + kk * 32 + kof];
#pragma unroll
            for (int mi = 0; mi < 4; ++mi)
#pragma unroll
                for (int ni = 0; ni < 4; ++ni)
                    acc[mi][ni] = __builtin_amdgcn_mfma_f32_16x16x32_bf16(a[mi], b[ni], acc[mi][ni], 0, 0, 0);
        }
        pa = pan;
        pb = pbn;
    }

    unsigned short* Cp = C + (long)z * NN * DO_;
#pragma unroll
    for (int mi = 0; mi < 4; ++mi)
#pragma unroll
        for (int ni = 0; ni < 4; ++ni) {
            const long col = wc + ni * 16 + (l & 15);
            const long rbase = row0 + wr + mi * 16 + ((l >> 4) << 2);
            f32x4 v = acc[mi][ni];
#pragma unroll
            for (int j = 0; j < 4; ++j) Cp[(rbase + j) * DO_ + col] = f2bf(v[j]);
        }
}

// ---- CSR gather D=256 ----
__device__ void dev_g256(int row, const float* __restrict__ h,
                         const int* __restrict__ rs, const int* __restrict__ csrc,
                         const float* __restrict__ norm, const float* __restrict__ bias,
                         unsigned short* __restrict__ outh, unsigned short* __restrict__ outl) {
    __shared__ int   sh_s[256];
    __shared__ float sh_ns[256];
    __shared__ float shred[4 * 256];
    const int tid = threadIdx.x, wv = tid >> 6, l = tid & 63;
    const int beg = rs[row], end = rs[row + 1];
    float4 acc = make_float4(0.f, 0.f, 0.f, 0.f);
    for (int base = beg; base < end; base += 256) {
        __syncthreads();
        if (base + tid < end) {
            int s = csrc[base + tid];
            sh_s[tid] = s;
            sh_ns[tid] = norm[s];
        }
        __syncthreads();
        int cnt = min(256, end - base);
        for (int j = wv; j < cnt; j += 4) {
            int s = sh_s[j];
            float ns = sh_ns[j];
            float4 hv = *(const float4*)&h[((long)s << 8) + (l << 2)];
            acc.x += hv.x * ns; acc.y += hv.y * ns; acc.z += hv.z * ns; acc.w += hv.w * ns;
        }
    }
    __syncthreads();
    *(float4*)&shred[wv * 256 + (l << 2)] = acc;
    __syncthreads();
    float val = shred[tid] + shred[256 + tid] + shred[512 + tid] + shred[768 + tid];
    float r = fmaxf(val * norm[row] + bias[tid], 0.f);
    unsigned short hb = f2bf(r);
    outh[((long)row << 8) + tid] = hb;
    outl[((long)row << 8) + tid] = f2bf(r - bf2f(hb));
}

// ---- CSR gather D=128 ----
__device__ void dev_g128(int row, const float* __restrict__ h,
                         const int* __restrict__ rs, const int* __restrict__ csrc,
                         const float* __restrict__ norm, const float* __restrict__ bias,
                         float* __restrict__ out) {
    __shared__ int   sh_s2[256];
    __shared__ float sh_ns2[256];
    __shared__ float shred2[4 * 128];
    const int tid = threadIdx.x, wv = tid >> 6, l = tid & 63;
    const int beg = rs[row], end = rs[row + 1];
    float2 acc = make_float2(0.f, 0.f);
    for (int base = beg; base < end; base += 256) {
        __syncthreads();
        if (base + tid < end) {
            int s = csrc[base + tid];
            sh_s2[tid] = s;
            sh_ns2[tid] = norm[s];
        }
        __syncthreads();
        int cnt = min(256, end - base);
        for (int j = wv; j < cnt; j += 4) {
            int s = sh_s2[j];
            float ns = sh_ns2[j];
            float2 hv = *(const float2*)&h[((long)s << 7) + (l << 1)];
            acc.x += hv.x * ns; acc.y += hv.y * ns;
        }
    }
    __syncthreads();
    *(float2*)&shred2[wv * 128 + (l << 1)] = acc;
    __syncthreads();
    if (tid < 128) {
        float val = shred2[tid] + shred2[128 + tid] + shred2[256 + tid] + shred2[384 + tid];
        float r = fmaxf(val * norm[row] + bias[tid], 0.f);
        out[((long)row << 7) + tid] = r;
    }
}

// ---- combine1: g2 = relu(sum_{z<8} part1 * (1/8192) + b1g) bf16 ----
__device__ void dev_c1(int idx, const unsigned short* __restrict__ part,
                       unsigned short* __restrict__ out, const float* __restrict__ bias) {
    int n4 = DH >> 2;
    if (idx >= NN * n4) return;
    int m = idx / n4, c = idx % n4;
    float4 s = make_float4(0.f, 0.f, 0.f, 0.f);
    for (int z = 0; z < 8; ++z) {
        u16x4 p = *(const u16x4*)&part[((long)z * NN + m) * DH + (c << 2)];
        s.x += bf2f(p.x); s.y += bf2f(p.y); s.z += bf2f(p.z); s.w += bf2f(p.w);
    }
    const float inv8192 = 1.0f / 8192.0f;
    float4 b = *(const float4*)&bias[c << 2];
    u16x4 o;
    o.x = f2bf(fmaxf(s.x * inv8192 + b.x, 0.f));
    o.y = f2bf(fmaxf(s.y * inv8192 + b.y, 0.f));
    o.z = f2bf(fmaxf(s.z * inv8192 + b.z, 0.f));
    o.w = f2bf(fmaxf(s.w * inv8192 + b.w, 0.f));
    *(u16x4*)&out[(long)m * DH + (c << 2)] = o;
}

// ---- eff transforms ----
__device__ void dev_eff_split(int idx, const float* __restrict__ w, const float* __restrict__ tao,
                              unsigned short* __restrict__ th, unsigned short* __restrict__ tl,
                              int I, int K0, int J) {
    if (idx >= I * J) return;
    int j = idx % J, i = idx / J;
    float s = 0.f;
    for (int k = 0; k < K0; ++k) s += w[i * K0 + k] * tao[k * J + j];
    unsigned short h = f2bf(s);
    th[j * I + i] = h;
    tl[j * I + i] = f2bf(s - bf2f(h));
}
__device__ void dev_eff_hi(int idx, const float* __restrict__ w, const float* __restrict__ tao,
                           unsigned short* __restrict__ th, int I, int K0, int J) {
    if (idx >= I * J) return;
    int j = idx % J, i = idx / J;
    float s = 0.f;
    for (int k = 0; k < K0; ++k) s += w[i * K0 + k] * tao[k * J + j];
    th[j * I + i] = f2bf(s);
}

// ---- CSR scan ----
__device__ void dev_scan256(const int* __restrict__ deg, int* __restrict__ rs, int* __restrict__ cur) {
    __shared__ int sums[256];
    int t = threadIdx.x;
    int loc[32];
    int s = 0;
#pragma unroll
    for (int j = 0; j < 32; ++j) { loc[j] = deg[t * 32 + j]; s += loc[j]; }
    sums[t] = s;
    __syncthreads();
    for (int off = 1; off < 256; off <<= 1) {
        int v = (t >= off) ? sums[t - off] : 0;
        __syncthreads();
        sums[t] += v;
        __syncthreads();
    }
    int base = (t > 0) ? sums[t - 1] : 0;
#pragma unroll
    for (int j = 0; j < 32; ++j) {
        rs[t * 32 + j] = base;
        cur[t * 32 + j] = base;
        base += loc[j];
    }
    if (t == 255) rs[NN] = base;
}

// ================= fused dispatch kernels =================

// S1: hist | eff1 | eff2 | eff3(hi) | eff4(hi)
__global__ __launch_bounds__(256) void k_s1(
    const int* __restrict__ dst, int* __restrict__ deg,
    const float* w1, const float* t1, unsigned short* e1h, unsigned short* e1l,
    const float* w2, const float* t2, unsigned short* e2h, unsigned short* e2l,
    const float* w3, const float* t3, unsigned short* e3h,
    const float* w4, const float* t4, unsigned short* e4h) {
    int b = blockIdx.x;
    if (b < 1024) {
        int e = b * 256 + threadIdx.x;
        atomicAdd(&deg[dst[e]], 1);
    } else if (b < 1536) {
        dev_eff_split((b - 1024) * 256 + threadIdx.x, w1, t1, e1h, e1l, DIN, DH, DH);
    } else if (b < 1664) {
        dev_eff_split((b - 1536) * 256 + threadIdx.x, w2, t2, e2h, e2l, DH, DO_, DO_);
    } else if (b < 2176) {
        dev_eff_hi((b - 1664) * 256 + threadIdx.x, w3, t3, e3h, DIN, DH, DH);
    } else {
        dev_eff_hi((b - 2176) * 256 + threadIdx.x, w4, t4, e4h, DH, DO_, DO_);
    }
}

// S2: LS1 (128) | GB1 (128) | scan (1) | PPMI u8 quantize (16384)
__global__ __launch_bounds__(256) void k_s2(
    const float* __restrict__ feats,
    const unsigned short* w1lh, const unsigned short* w1ll, float* h0,
    const unsigned short* w1gh, unsigned short* g0t,
    const int* deg, int* rs, int* cur,
    const float* __restrict__ PPMI, unsigned char* __restrict__ ppmi8) {
    int b = blockIdx.x;
    if (b < 128)      dev_ls1(b & 63, b >> 6, feats, w1lh, w1ll, h0);
    else if (b < 256) dev_gb1((b - 128) & 63, (b - 128) >> 6, feats, w1gh, g0t);
    else if (b == 256) dev_scan256(deg, rs, cur);
    else {
        long i = (long)(b - 257) * 256 + threadIdx.x;
        const float4* p = (const float4*)PPMI + i * 4;
        uint4 o;
        o.x = pack4_u8(p[0]);
        o.y = pack4_u8(p[1]);
        o.z = pack4_u8(p[2]);
        o.w = pack4_u8(p[3]);
        ((uint4*)ppmi8)[i] = o;
    }
}

// S3 (512 threads): P1 (64x8, BK=64, u8 A) | fill
__global__ __launch_bounds__(512) void k_s3(
    const unsigned char* __restrict__ ppmi8, const unsigned short* g0t, unsigned short* part1,
    const int* __restrict__ src, const int* __restrict__ dst, int* cur, int* csrc) {
    int b = blockIdx.x;
    if (b < 512) {
        dev_ppmi1(b & 63, b >> 6, ppmi8, g0t, part1);
    } else {
        int e = (b - 512) * 512 + threadIdx.x;
        int pos = atomicAdd(&cur[dst[e]], 1);
        csrc[pos] = src[e];
    }
}

// S4: gather256 (8192) | combine1 (2048)
__global__ __launch_bounds__(256) void k_s4(
    const float* h0, const int* rs, const int* csrc, const float* norm, const float* b1,
    unsigned short* h1h, unsigned short* h1l,
    const unsigned short* part1, unsigned short* g2, const float* b1g) {
    int b = blockIdx.x;
    if (b < 8192) dev_g256(b, h0, rs, csrc, norm, b1, h1h, h1l);
    else          dev_c1((b - 8192) * 256 + threadIdx.x, part1, g2, b1g);
}

// S5: LS2 (64) | GB2 (64)
__global__ __launch_bounds__(256) void k_s5(
    const unsigned short* h1h, const unsigned short* h1l,
    const unsigned short* w2lh, const unsigned short* w2ll, float* h2,
    const unsigned short* g2, const unsigned short* w2gh, unsigned short* g3t) {
    int b = blockIdx.x;
    if (b < 64) dev_gemm_split(b, 0, h1h, h1l, w2lh, w2ll, h2, NN, DO_, DH);
    else        dev_gemm_b1(b - 64, 0, g2, w2gh, g3t, NN, DO_, DH);
}

// S6: P2 (64x8, BK=64, u8 A) | gather128 (8192)
__global__ __launch_bounds__(256) void k_s6(
    const unsigned char* __restrict__ ppmi8, const unsigned short* g3t, unsigned short* part2,
    const float* h2, const int* rs, const int* csrc, const float* norm, const float* b2,
    float* HL) {
    int b = blockIdx.x;
    if (b < 512) dev_ppmi2(b & 63, b >> 6, ppmi8, g3t, part2);
    else         dev_g128(b - 512, h2, rs, csrc, norm, b2, HL);
}

// S7: attn + fused combine2 (part2 carries x8192 scale -> remove before bias)
__global__ __launch_bounds__(256) void k_s7(
    const float* __restrict__ HL, const unsigned short* __restrict__ part2,
    const float* __restrict__ b2g,
    const float* __restrict__ Wa, const float* __restrict__ Wc,
    const float* __restrict__ bc, float* __restrict__ out) {
    int wv = threadIdx.x >> 6, l = threadIdx.x & 63;
    int row = blockIdx.x * 4 + wv;
    float2 hg = make_float2(0.f, 0.f);
#pragma unroll
    for (int z = 0; z < 8; ++z) {
        unsigned int u = *(const unsigned int*)&part2[((long)z * NN + row) * DO_ + 2 * l];
        hg.x += bf2f((unsigned short)(u & 0xffffu));
        hg.y += bf2f((unsigned short)(u >> 16));
    }
    const float inv8192 = 1.0f / 8192.0f;
    float2 bg = *(const float2*)&b2g[2 * l];
    hg.x = fmaxf(hg.x * inv8192 + bg.x, 0.f);
    hg.y = fmaxf(hg.y * inv8192 + bg.y, 0.f);

    float2 hl = *(const float2*)&HL[(long)row * DO_ + l * 2];
    float4 wa0 = *(const float4*)&Wa[(2 * l) * 2];
    float4 wa1 = *(const float4*)&Wa[(DO_ + 2 * l) * 2];
    float p0 = hl.x * wa0.x + hl.y * wa0.z + hg.x * wa1.x + hg.y * wa1.z;
    float p1 = hl.x * wa0.y + hl.y * wa0.w + hg.x * wa1.y + hg.y * wa1.w;
#pragma unroll
    for (int off = 32; off >= 1; off >>= 1) {
        p0 += __shfl_xor(p0, off);
        p1 += __shfl_xor(p1, off);
    }
    float mx = fmaxf(p0, p1);
    float e0 = __expf(p0 - mx), e1 = __expf(p1 - mx);
    float inv = 1.f / (e0 + e1);
    float a0 = e0 * inv, a1 = e1 * inv;
    float z0 = a0 * hl.x + a1 * hg.x;
    float z1 = a0 * hl.y + a1 * hg.y;
    float4 wcA0 = *(const float4*)&Wc[(2 * l) * NCLS];
    float4 wcA1 = *(const float4*)&Wc[(2 * l) * NCLS + 4];
    float4 wcB0 = *(const float4*)&Wc[(2 * l + 1) * NCLS];
    float4 wcB1 = *(const float4*)&Wc[(2 * l + 1) * NCLS + 4];
    float q0 = z0 * wcA0.x + z1 * wcB0.x;
    float q1 = z0 * wcA0.y + z1 * wcB0.y;
    float q2 = z0 * wcA0.z + z1 * wcB0.z;
    float q3 = z0 * wcA0.w + z1 * wcB0.w;
    float q4 = z0 * wcA1.x + z1 * wcB1.x;
    float q5 = z0 * wcA1.y + z1 * wcB1.y;
    float q6 = z0 * wcA1.z + z1 * wcB1.z;
    float q7 = z0 * wcA1.w + z1 * wcB1.w;
#pragma unroll
    for (int off = 32; off >= 1; off >>= 1) {
        q0 += __shfl_xor(q0, off); q1 += __shfl_xor(q1, off);
        q2 += __shfl_xor(q2, off); q3 += __shfl_xor(q3, off);
        q4 += __shfl_xor(q4, off); q5 += __shfl_xor(q5, off);
        q6 += __shfl_xor(q6, off); q7 += __shfl_xor(q7, off);
    }
    if (l == 0) {
        float* o = &out[(long)row * NCLS];
        o[0] = q0 + bc[0]; o[1] = q1 + bc[1]; o[2] = q2 + bc[2]; o[3] = q3 + bc[3];
        o[4] = q4 + bc[4]; o[5] = q5 + bc[5]; o[6] = q6 + bc[6]; o[7] = q7 + bc[7];
    }
}

extern "C" void kernel_launch(void* const* d_in, const int* in_sizes, int n_in,
                              void* d_out, int out_size, void* d_ws, size_t ws_size,
                              hipStream_t stream) {
    (void)in_sizes; (void)n_in; (void)out_size; (void)ws_size;
    const float* feats = (const float*)d_in[0];
    const float* norm  = (const float*)d_in[1];
    const float* tao1L = (const float*)d_in[2];
    const float* tao2L = (const float*)d_in[3];
    const float* tao1G = (const float*)d_in[4];
    const float* tao2G = (const float*)d_in[5];
    const float* PPMI  = (const float*)d_in[6];
    const float* w1  = (const float*)d_in[7];
    const float* b1  = (const float*)d_in[8];
    const float* w2  = (const float*)d_in[9];
    const float* b2  = (const float*)d_in[10];
    const float* w1g = (const float*)d_in[11];
    const float* b1g = (const float*)d_in[12];
    const float* w2g = (const float*)d_in[13];
    const float* b2g = (const float*)d_in[14];
    const float* Wa  = (const float*)d_in[15];
    const float* Wc  = (const float*)d_in[16];
    const float* bc  = (const float*)d_in[17];
    const int* src = (const int*)d_in[18];
    const int* dst = (const int*)d_in[19];

    char* ws = (char*)d_ws;
    size_t off = 0;
    auto alloc = [&](size_t b) { void* p = (void*)(ws + off); off += (b + 255) & ~(size_t)255; return p; };
    unsigned short* w1lh = (unsigned short*)alloc((size_t)DH * DIN * 2);
    unsigned short* w1ll = (unsigned short*)alloc((size_t)DH * DIN * 2);
    unsigned short* w2lh = (unsigned short*)alloc((size_t)DO_ * DH * 2);
    unsigned short* w2ll = (unsigned short*)alloc((size_t)DO_ * DH * 2);
    unsigned short* w1gh = (unsigned short*)alloc((size_t)DH * DIN * 2);
    unsigned short* w2gh = (unsigned short*)alloc((size_t)DO_ * DH * 2);
    unsigned short* g0t = (unsigned short*)alloc((size_t)DH * NN * 2);
    unsigned short* g2  = (unsigned short*)alloc((size_t)NN * DH * 2);
    unsigned short* g3t = (unsigned short*)alloc((size_t)DO_ * NN * 2);
    unsigned short* h1h = (unsigned short*)alloc((size_t)NN * DH * 2);
    unsigned short* h1l = (unsigned short*)alloc((size_t)NN * DH * 2);
    float* h0 = (float*)alloc((size_t)NN * DH * 4);
    float* h2 = (float*)alloc((size_t)NN * DO_ * 4);
    float* HL = (float*)alloc((size_t)NN * DO_ * 4);
    unsigned short* part1 = (unsigned short*)alloc((size_t)8 * NN * DH * 2);   // 33.5 MB
    unsigned short* part2 = (unsigned short*)alloc((size_t)8 * NN * DO_ * 2);  // 16.8 MB
    unsigned char* ppmi8 = (unsigned char*)alloc((size_t)NN * NN);             // 67 MB
    int* deg  = (int*)alloc((size_t)NN * 4);
    int* rs   = (int*)alloc((size_t)(NN + 1) * 4);
    int* cur  = (int*)alloc((size_t)NN * 4);
    int* csrc = (int*)alloc((size_t)NE * 4);

    hipMemsetAsync(deg, 0, (size_t)NN * 4, stream);

    // S1: hist | eff transforms
    k_s1<<<dim3(2304), dim3(256), 0, stream>>>(
        dst, deg,
        w1,  tao1L, w1lh, w1ll,
        w2,  tao2L, w2lh, w2ll,
        w1g, tao1G, w1gh,
        w2g, tao2G, w2gh);

    // S2: LS1 | GB1 | scan | PPMI->u8 quantize
    k_s2<<<dim3(16641), dim3(256), 0, stream>>>(feats, w1lh, w1ll, h0, w1gh, g0t,
                                                deg, rs, cur, PPMI, ppmi8);

    // S3: P1 (BK=64, z=8, u8 A) | fill
    k_s3<<<dim3(1024), dim3(512), 0, stream>>>(ppmi8, g0t, part1, src, dst, cur, csrc);

    // S4: gather256 | combine1 (Z=8, removes x8192 scale)
    k_s4<<<dim3(10240), dim3(256), 0, stream>>>(h0, rs, csrc, norm, b1, h1h, h1l, part1, g2, b1g);

    // S5: LS2 | GB2
    k_s5<<<dim3(128), dim3(256), 0, stream>>>(h1h, h1l, w2lh, w2ll, h2, g2, w2gh, g3t);

    // S6: P2 (BK=64, z=8, u8 A) | gather128
    k_s6<<<dim3(8704), dim3(256), 0, stream>>>(ppmi8, g3t, part2, h2, rs, csrc, norm, b2, HL);

    // S7: attn + fused combine2 (removes x8192 scale)
    k_s7<<<dim3(2048), dim3(256), 0, stream>>>(HL, part2, b2g, Wa, Wc, bc, (float*)d_out);
}

// Round 17
// 292.444 us; speedup vs baseline: 1.0935x; 1.0935x over previous
//
#include <hip/hip_runtime.h>
#include <hip/hip_bf16.h>

#define NN 8192
#define DIN 512
#define DH 256
#define DO_ 128
#define NCLS 8
#define NE 262144

typedef __attribute__((ext_vector_type(8))) short bf16x8;
typedef __attribute__((ext_vector_type(4))) float f32x4;
typedef __attribute__((ext_vector_type(4))) unsigned short u16x4;
typedef __attribute__((ext_vector_type(8))) unsigned short u16x8;

__device__ __forceinline__ unsigned short f2bf(float x) {
    unsigned int u = __float_as_uint(x);
    return (unsigned short)((u + 0x7FFFu + ((u >> 16) & 1u)) >> 16);
}
__device__ __forceinline__ float bf2f(unsigned short h) {
    return __uint_as_float((unsigned int)h << 16);
}

#define GLDS(gp, lp) __builtin_amdgcn_global_load_lds( \
    (const __attribute__((address_space(1))) void*)(gp), \
    (__attribute__((address_space(3))) void*)(lp), 16, 0, 0)

__device__ __forceinline__ void cvt8_store(unsigned short* dst, float4 a, float4 b) {
    u16x8 o;
    o[0] = f2bf(a.x); o[1] = f2bf(a.y); o[2] = f2bf(a.z); o[3] = f2bf(a.w);
    o[4] = f2bf(b.x); o[5] = f2bf(b.y); o[6] = f2bf(b.z); o[7] = f2bf(b.w);
    *(u16x8*)dst = o;
}
__device__ __forceinline__ void cvt8_split_store(unsigned short* dH, unsigned short* dL, float4 a, float4 b) {
    u16x8 oh, ol;
    unsigned short h;
    h = f2bf(a.x); oh[0] = h; ol[0] = f2bf(a.x - bf2f(h));
    h = f2bf(a.y); oh[1] = h; ol[1] = f2bf(a.y - bf2f(h));
    h = f2bf(a.z); oh[2] = h; ol[2] = f2bf(a.z - bf2f(h));
    h = f2bf(a.w); oh[3] = h; ol[3] = f2bf(a.w - bf2f(h));
    h = f2bf(b.x); oh[4] = h; ol[4] = f2bf(b.x - bf2f(h));
    h = f2bf(b.y); oh[5] = h; ol[5] = f2bf(b.y - bf2f(h));
    h = f2bf(b.z); oh[6] = h; ol[6] = f2bf(b.z - bf2f(h));
    h = f2bf(b.w); oh[7] = h; ol[7] = f2bf(b.w - bf2f(h));
    *(u16x8*)dH = oh;
    *(u16x8*)dL = ol;
}

// u8 fixed-point encode of PPMI (x in [0,1/8192)): u = round(x * 8192 * 255)
#define U8SCALE 2088960.0f
__device__ __forceinline__ unsigned int pack4_u8(float4 v) {
    unsigned int b0 = (unsigned int)(v.x * U8SCALE + 0.5f);
    unsigned int b1 = (unsigned int)(v.y * U8SCALE + 0.5f);
    unsigned int b2 = (unsigned int)(v.z * U8SCALE + 0.5f);
    unsigned int b3 = (unsigned int)(v.w * U8SCALE + 0.5f);
    return b0 | (b1 << 8) | (b2 << 16) | (b3 << 24);
}
__device__ __forceinline__ float4 dec4_u8(unsigned int d) {
    const float s = 1.0f / 255.0f;
    return make_float4((float)(d & 255u) * s, (float)((d >> 8) & 255u) * s,
                       (float)((d >> 16) & 255u) * s, (float)(d >> 24) * s);
}

// ================= compute bodies =================

// ---- LS1: h0 = feats(f32, inline hi/lo split) @ w1l_eff^T, 3-term split MFMA ----
__device__ void dev_ls1(int bx, int by, const float* __restrict__ A,
                        const unsigned short* __restrict__ Bh, const unsigned short* __restrict__ Bl,
                        float* __restrict__ C) {
    __shared__ unsigned short AsH[128 * 32];
    __shared__ unsigned short AsL[128 * 32];
    __shared__ unsigned short BsH[128 * 32];
    __shared__ unsigned short BsL[128 * 32];
    const int t = threadIdx.x;
    const int w = t >> 6;
    const int l = t & 63;
    const int wr = (w >> 1) * 64;
    const int wc = (w & 1) * 64;
    const long row0 = (long)bx * 128;
    const long col0 = (long)by * 128;
    const int K = DIN;
    const int nk = DIN >> 5;

    f32x4 acc[4][4];
#pragma unroll
    for (int mi = 0; mi < 4; ++mi)
#pragma unroll
        for (int ni = 0; ni < 4; ++ni) { f32x4 z = {0.f,0.f,0.f,0.f}; acc[mi][ni] = z; }

    const int ar = t >> 1;
    const int akh = (t & 1) << 4;
    const float* Abase = A + (row0 + ar) * K + akh;
    const int aoff = ar * 32 + akh;
    const int srow = (w << 4) + (l >> 2);
    const int skk  = (l & 3) << 3;
    const unsigned short* BhB = Bh + (col0 + srow) * K + skk;
    const unsigned short* BlB = Bl + (col0 + srow) * K + skk;
    unsigned short* BsHW = &BsH[w << 9];
    unsigned short* BsLW = &BsL[w << 9];

    for (int kt = 0; kt < nk; ++kt) {
        const long ko = (long)kt << 5;
        __syncthreads();
        float4 fa0 = *(const float4*)(Abase + ko);
        float4 fa1 = *(const float4*)(Abase + ko + 4);
        float4 fa2 = *(const float4*)(Abase + ko + 8);
        float4 fa3 = *(const float4*)(Abase + ko + 12);
        GLDS(BhB + ko,                BsHW);
        GLDS(BhB + (long)64 * K + ko, BsHW + 2048);
        GLDS(BlB + ko,                BsLW);
        GLDS(BlB + (long)64 * K + ko, BsLW + 2048);
        cvt8_split_store(&AsH[aoff],     &AsL[aoff],     fa0, fa1);
        cvt8_split_store(&AsH[aoff + 8], &AsL[aoff + 8], fa2, fa3);
        __syncthreads();

        const int ro  = (l & 15);
        const int kof = (l >> 4) << 3;
        bf16x8 ah[4], al[4], bh[4], bl[4];
#pragma unroll
        for (int mi = 0; mi < 4; ++mi) {
            ah[mi] = *(const bf16x8*)&AsH[(wr + mi * 16 + ro) * 32 + kof];
            al[mi] = *(const bf16x8*)&AsL[(wr + mi * 16 + ro) * 32 + kof];
        }
#pragma unroll
        for (int ni = 0; ni < 4; ++ni) {
            bh[ni] = *(const bf16x8*)&BsH[(wc + ni * 16 + ro) * 32 + kof];
            bl[ni] = *(const bf16x8*)&BsL[(wc + ni * 16 + ro) * 32 + kof];
        }
#pragma unroll
        for (int mi = 0; mi < 4; ++mi)
#pragma unroll
            for (int ni = 0; ni < 4; ++ni) {
                acc[mi][ni] = __builtin_amdgcn_mfma_f32_16x16x32_bf16(ah[mi], bl[ni], acc[mi][ni], 0, 0, 0);
                acc[mi][ni] = __builtin_amdgcn_mfma_f32_16x16x32_bf16(al[mi], bh[ni], acc[mi][ni], 0, 0, 0);
                acc[mi][ni] = __builtin_amdgcn_mfma_f32_16x16x32_bf16(ah[mi], bh[ni], acc[mi][ni], 0, 0, 0);
            }
    }
#pragma unroll
    for (int mi = 0; mi < 4; ++mi)
#pragma unroll
        for (int ni = 0; ni < 4; ++ni) {
            const long col = col0 + wc + ni * 16 + (l & 15);
            const long rbase = row0 + wr + mi * 16 + ((l >> 4) << 2);
            f32x4 v = acc[mi][ni];
#pragma unroll
            for (int j = 0; j < 4; ++j) C[(rbase + j) * DH + col] = v[j];
        }
}

// ---- LS2: split-bf16 3-term GEMM, A bf16 hi/lo from global ----
__device__ void dev_gemm_split(int bx, int by,
                               const unsigned short* __restrict__ Ah, const unsigned short* __restrict__ Al,
                               const unsigned short* __restrict__ Bh, const unsigned short* __restrict__ Bl,
                               float* __restrict__ C, int M, int N, int K) {
    __shared__ unsigned short AsH2[128 * 32];
    __shared__ unsigned short AsL2[128 * 32];
    __shared__ unsigned short BsH2[128 * 32];
    __shared__ unsigned short BsL2[128 * 32];
    const int t = threadIdx.x;
    const int w = t >> 6;
    const int l = t & 63;
    const int wr = (w >> 1) * 64;
    const int wc = (w & 1) * 64;
    const long row0 = (long)bx * 128;
    const long col0 = (long)by * 128;
    const int nk = K >> 5;

    f32x4 acc[4][4];
#pragma unroll
    for (int mi = 0; mi < 4; ++mi)
#pragma unroll
        for (int ni = 0; ni < 4; ++ni) { f32x4 z = {0.f,0.f,0.f,0.f}; acc[mi][ni] = z; }

    const int srow = (w << 4) + (l >> 2);
    const int skk  = (l & 3) << 3;
    const long aoff = row0 * K + skk;
    const long boff = col0 * K + skk;
    unsigned short* AsHW = &AsH2[w << 9];
    unsigned short* AsLW = &AsL2[w << 9];
    unsigned short* BsHW = &BsH2[w << 9];
    unsigned short* BsLW = &BsL2[w << 9];

    for (int kt = 0; kt < nk; ++kt) {
        const long ko = (long)kt << 5;
        __syncthreads();
        GLDS(Ah + aoff + (long)srow * K + ko,        AsHW);
        GLDS(Ah + aoff + (long)(srow + 64) * K + ko, AsHW + 2048);
        GLDS(Al + aoff + (long)srow * K + ko,        AsLW);
        GLDS(Al + aoff + (long)(srow + 64) * K + ko, AsLW + 2048);
        GLDS(Bh + boff + (long)srow * K + ko,        BsHW);
        GLDS(Bh + boff + (long)(srow + 64) * K + ko, BsHW + 2048);
        GLDS(Bl + boff + (long)srow * K + ko,        BsLW);
        GLDS(Bl + boff + (long)(srow + 64) * K + ko, BsLW + 2048);
        __syncthreads();

        const int ro  = (l & 15);
        const int kof = (l >> 4) << 3;
        bf16x8 ah[4], al[4], bh[4], bl[4];
#pragma unroll
        for (int mi = 0; mi < 4; ++mi) {
            ah[mi] = *(const bf16x8*)&AsH2[(wr + mi * 16 + ro) * 32 + kof];
            al[mi] = *(const bf16x8*)&AsL2[(wr + mi * 16 + ro) * 32 + kof];
        }
#pragma unroll
        for (int ni = 0; ni < 4; ++ni) {
            bh[ni] = *(const bf16x8*)&BsH2[(wc + ni * 16 + ro) * 32 + kof];
            bl[ni] = *(const bf16x8*)&BsL2[(wc + ni * 16 + ro) * 32 + kof];
        }
#pragma unroll
        for (int mi = 0; mi < 4; ++mi)
#pragma unroll
            for (int ni = 0; ni < 4; ++ni) {
                acc[mi][ni] = __builtin_amdgcn_mfma_f32_16x16x32_bf16(ah[mi], bl[ni], acc[mi][ni], 0, 0, 0);
                acc[mi][ni] = __builtin_amdgcn_mfma_f32_16x16x32_bf16(al[mi], bh[ni], acc[mi][ni], 0, 0, 0);
                acc[mi][ni] = __builtin_amdgcn_mfma_f32_16x16x32_bf16(ah[mi], bh[ni], acc[mi][ni], 0, 0, 0);
            }
    }
#pragma unroll
    for (int mi = 0; mi < 4; ++mi)
#pragma unroll
        for (int ni = 0; ni < 4; ++ni) {
            const long col = col0 + wc + ni * 16 + (l & 15);
            const long rbase = row0 + wr + mi * 16 + ((l >> 4) << 2);
            f32x4 v = acc[mi][ni];
#pragma unroll
            for (int j = 0; j < 4; ++j) C[(rbase + j) * N + col] = v[j];
        }
}

// ---- GB1: g0t = (feats(f32->bf16 hi, inline) @ w1g_eff)^T ----
__device__ void dev_gb1(int bx, int by, const float* __restrict__ A,
                        const unsigned short* __restrict__ B, unsigned short* __restrict__ C) {
    __shared__ unsigned short AsG[128 * 32];
    __shared__ unsigned short BsG[128 * 32];
    const int t = threadIdx.x;
    const int w = t >> 6;
    const int l = t & 63;
    const int wr = (w >> 1) * 64;
    const int wc = (w & 1) * 64;
    const long row0 = (long)bx * 128;
    const long col0 = (long)by * 128;
    const int K = DIN;
    const int nk = DIN >> 5;

    f32x4 acc[4][4];
#pragma unroll
    for (int mi = 0; mi < 4; ++mi)
#pragma unroll
        for (int ni = 0; ni < 4; ++ni) { f32x4 z = {0.f,0.f,0.f,0.f}; acc[mi][ni] = z; }

    const int ar = t >> 1;
    const int akh = (t & 1) << 4;
    const float* Abase = A + (row0 + ar) * K + akh;
    const int aoff = ar * 32 + akh;
    const int srow = (w << 4) + (l >> 2);
    const int skk  = (l & 3) << 3;
    const unsigned short* Bbase = B + (col0 + srow) * K + skk;
    unsigned short* BsW = &BsG[w << 9];

    for (int kt = 0; kt < nk; ++kt) {
        const long ko = (long)kt << 5;
        __syncthreads();
        float4 fa0 = *(const float4*)(Abase + ko);
        float4 fa1 = *(const float4*)(Abase + ko + 4);
        float4 fa2 = *(const float4*)(Abase + ko + 8);
        float4 fa3 = *(const float4*)(Abase + ko + 12);
        GLDS(Bbase + ko,                BsW);
        GLDS(Bbase + (long)64 * K + ko, BsW + 2048);
        cvt8_store(&AsG[aoff],     fa0, fa1);
        cvt8_store(&AsG[aoff + 8], fa2, fa3);
        __syncthreads();

        const int ro  = (l & 15);
        const int kof = (l >> 4) << 3;
        bf16x8 a[4], b[4];
#pragma unroll
        for (int mi = 0; mi < 4; ++mi)
            a[mi] = *(const bf16x8*)&AsG[(wr + mi * 16 + ro) * 32 + kof];
#pragma unroll
        for (int ni = 0; ni < 4; ++ni)
            b[ni] = *(const bf16x8*)&BsG[(wc + ni * 16 + ro) * 32 + kof];
#pragma unroll
        for (int mi = 0; mi < 4; ++mi)
#pragma unroll
            for (int ni = 0; ni < 4; ++ni)
                acc[mi][ni] = __builtin_amdgcn_mfma_f32_16x16x32_bf16(a[mi], b[ni], acc[mi][ni], 0, 0, 0);
    }
#pragma unroll
    for (int mi = 0; mi < 4; ++mi)
#pragma unroll
        for (int ni = 0; ni < 4; ++ni) {
            const long col = col0 + wc + ni * 16 + (l & 15);
            const long rbase = row0 + wr + mi * 16 + ((l >> 4) << 2);
            f32x4 v = acc[mi][ni];
            u16x4 o;
            o.x = f2bf(v[0]); o.y = f2bf(v[1]); o.z = f2bf(v[2]); o.w = f2bf(v[3]);
            *(u16x4*)(C + col * NN + rbase) = o;
        }
}

// ---- GB2: single-bf16 GEMM, bf16 [N,M] transposed out ----
__device__ void dev_gemm_b1(int bx, int by,
                            const unsigned short* __restrict__ A, const unsigned short* __restrict__ B,
                            unsigned short* __restrict__ C, int M, int N, int K) {
    __shared__ unsigned short As1[128 * 32];
    __shared__ unsigned short Bs1[128 * 32];
    const int t = threadIdx.x;
    const int w = t >> 6;
    const int l = t & 63;
    const int wr = (w >> 1) * 64;
    const int wc = (w & 1) * 64;
    const long row0 = (long)bx * 128;
    const long col0 = (long)by * 128;
    const int nk = K >> 5;

    f32x4 acc[4][4];
#pragma unroll
    for (int mi = 0; mi < 4; ++mi)
#pragma unroll
        for (int ni = 0; ni < 4; ++ni) { f32x4 z = {0.f,0.f,0.f,0.f}; acc[mi][ni] = z; }

    const int srow = (w << 4) + (l >> 2);
    const int skk  = (l & 3) << 3;
    const unsigned short* Abase = A + row0 * K + skk;
    const unsigned short* Bbase = B + col0 * K + skk;
    unsigned short* AsW = &As1[w << 9];
    unsigned short* BsW = &Bs1[w << 9];

    for (int kt = 0; kt < nk; ++kt) {
        const long ko = (long)kt << 5;
        __syncthreads();
        GLDS(Abase + (long)srow * K + ko,        AsW);
        GLDS(Abase + (long)(srow + 64) * K + ko, AsW + 2048);
        GLDS(Bbase + (long)srow * K + ko,        BsW);
        GLDS(Bbase + (long)(srow + 64) * K + ko, BsW + 2048);
        __syncthreads();

        const int ro  = (l & 15);
        const int kof = (l >> 4) << 3;
        bf16x8 a[4], b[4];
#pragma unroll
        for (int mi = 0; mi < 4; ++mi)
            a[mi] = *(const bf16x8*)&As1[(wr + mi * 16 + ro) * 32 + kof];
#pragma unroll
        for (int ni = 0; ni < 4; ++ni)
            b[ni] = *(const bf16x8*)&Bs1[(wc + ni * 16 + ro) * 32 + kof];
#pragma unroll
        for (int mi = 0; mi < 4; ++mi)
#pragma unroll
            for (int ni = 0; ni < 4; ++ni)
                acc[mi][ni] = __builtin_amdgcn_mfma_f32_16x16x32_bf16(a[mi], b[ni], acc[mi][ni], 0, 0, 0);
    }
#pragma unroll
    for (int mi = 0; mi < 4; ++mi)
#pragma unroll
        for (int ni = 0; ni < 4; ++ni) {
            const long col = col0 + wc + ni * 16 + (l & 15);
            const long rbase = row0 + wr + mi * 16 + ((l >> 4) << 2);
            f32x4 v = acc[mi][ni];
            u16x4 o;
            o.x = f2bf(v[0]); o.y = f2bf(v[1]); o.z = f2bf(v[2]); o.w = f2bf(v[3]);
            *(u16x4*)(C + col * M + rbase) = o;
        }
}

// ---- PPMI GEMM 1 (512 thr, BM=128 BN=256, z=16): u8 A, XOR cg-swizzled LDS ----
__device__ void dev_ppmi1(int bx, int z, const unsigned char* __restrict__ A8,
                          const unsigned short* __restrict__ B, unsigned short* __restrict__ C) {
    __shared__ unsigned short AsP[128 * 32];
    __shared__ unsigned short BsP[256 * 32];
    const int t = threadIdx.x;
    const int w = t >> 6;
    const int l = t & 63;
    const int wr = (w >> 2) * 64;
    const int wc = (w & 3) * 64;
    const long row0 = (long)bx * 128;
    const long kbeg = (long)z * (NN / 16);
    const int nk = (NN / 16) >> 5;
    const int K = NN;

    f32x4 acc[4][4];
#pragma unroll
    for (int mi = 0; mi < 4; ++mi)
#pragma unroll
        for (int ni = 0; ni < 4; ++ni) { f32x4 zz = {0.f,0.f,0.f,0.f}; acc[mi][ni] = zz; }

    const int ar = t >> 2;
    const int akq = (t & 3) << 3;
    const int acg = (t & 3) ^ ((ar >> 1) & 3);
    const unsigned char* Abase = A8 + (row0 + ar) * (long)K + kbeg + akq;
    unsigned short* AsW = &AsP[ar * 32 + (acg << 3)];
    const int srow = (w << 4) + (l >> 2);
    const int skk  = (((l & 3) ^ ((srow >> 1) & 3)) << 3);
    const unsigned short* Bbase = B + (long)srow * K + kbeg + skk;
    unsigned short* BsW = &BsP[(w << 4) * 32];

    uint2 pa = *(const uint2*)(Abase);
    for (int kt = 0; kt < nk; ++kt) {
        const long ko = (long)kt << 5;
        __syncthreads();
        GLDS(Bbase + ko,                 BsW);
        GLDS(Bbase + (long)128 * K + ko, BsW + 128 * 32);
        float4 g0 = dec4_u8(pa.x);
        float4 g1 = dec4_u8(pa.y);
        cvt8_store(AsW, g0, g1);
        uint2 pn = pa;
        if (kt + 1 < nk) pn = *(const uint2*)(Abase + ko + 32);
        __syncthreads();

        const int ro  = (l & 15);
        const int kof = (((l >> 4) ^ ((ro >> 1) & 3)) << 3);
        bf16x8 a[4], b[4];
#pragma unroll
        for (int mi = 0; mi < 4; ++mi)
            a[mi] = *(const bf16x8*)&AsP[(wr + mi * 16 + ro) * 32 + kof];
#pragma unroll
        for (int ni = 0; ni < 4; ++ni)
            b[ni] = *(const bf16x8*)&BsP[(wc + ni * 16 + ro) * 32 + kof];
#pragma unroll
        for (int mi = 0; mi < 4; ++mi)
#pragma unroll
            for (int ni = 0; ni < 4; ++ni)
                acc[mi][ni] = __builtin_amdgcn_mfma_f32_16x16x32_bf16(a[mi], b[ni], acc[mi][ni], 0, 0, 0);
        pa = pn;
    }

    unsigned short* Cp = C + (long)z * NN * DH;
#pragma unroll
    for (int mi = 0; mi < 4; ++mi)
#pragma unroll
        for (int ni = 0; ni < 4; ++ni) {
            const long col = wc + ni * 16 + (l & 15);
            const long rbase = row0 + wr + mi * 16 + ((l >> 4) << 2);
            f32x4 v = acc[mi][ni];
#pragma unroll
            for (int j = 0; j < 4; ++j) Cp[(rbase + j) * DH + col] = f2bf(v[j]);
        }
}

// ---- PPMI GEMM 2 (256 thr, BM=128 BN=128, z=8): u8 A, XOR cg-swizzled LDS ----
__device__ void dev_ppmi2(int bx, int z, const unsigned char* __restrict__ A8,
                          const unsigned short* __restrict__ B, unsigned short* __restrict__ C) {
    __shared__ unsigned short AsQ[128 * 32];
    __shared__ unsigned short BsQ[128 * 32];
    const int t = threadIdx.x;
    const int w = t >> 6;
    const int l = t & 63;
    const int wr = (w >> 1) * 64;
    const int wc = (w & 1) * 64;
    const long row0 = (long)bx * 128;
    const long kbeg = (long)z * (NN / 8);
    const int nk = (NN / 8) >> 5;
    const int K = NN;

    f32x4 acc[4][4];
#pragma unroll
    for (int mi = 0; mi < 4; ++mi)
#pragma unroll
        for (int ni = 0; ni < 4; ++ni) { f32x4 zz = {0.f,0.f,0.f,0.f}; acc[mi][ni] = zz; }

    const int ar = t >> 1;
    const int akh = (t & 1) << 4;
    const int s0 = (ar >> 1) & 3;
    const int cg0 = (2 * (t & 1)) ^ s0;
    const int cg1 = (2 * (t & 1) + 1) ^ s0;
    const unsigned char* Abase = A8 + (row0 + ar) * (long)K + kbeg + akh;
    unsigned short* AsW0 = &AsQ[ar * 32 + (cg0 << 3)];
    unsigned short* AsW1 = &AsQ[ar * 32 + (cg1 << 3)];
    const int srow = (w << 4) + (l >> 2);
    const int skk  = (((l & 3) ^ ((srow >> 1) & 3)) << 3);
    const unsigned short* Bbase = B + (long)srow * K + kbeg + skk;
    unsigned short* BsW = &BsQ[w << 9];

    uint4 pa = *(const uint4*)(Abase);
    for (int kt = 0; kt < nk; ++kt) {
        const long ko = (long)kt << 5;
        __syncthreads();
        GLDS(Bbase + ko,                BsW);
        GLDS(Bbase + (long)64 * K + ko, BsW + 2048);
        float4 g0 = dec4_u8(pa.x);
        float4 g1 = dec4_u8(pa.y);
        float4 g2v = dec4_u8(pa.z);
        float4 g3v = dec4_u8(pa.w);
        cvt8_store(AsW0, g0, g1);
        cvt8_store(AsW1, g2v, g3v);
        uint4 pn = pa;
        if (kt + 1 < nk) pn = *(const uint4*)(Abase + ko + 32);
        __syncthreads();

        const int ro  = (l & 15);
        const int kof = (((l >> 4) ^ ((ro >> 1) & 3)) << 3);
        bf16x8 a[4], b[4];
#pragma unroll
        for (int mi = 0; mi < 4; ++mi)
            a[mi] = *(const bf16x8*)&AsQ[(wr + mi * 16 + ro) * 32 + kof];
#pragma unroll
        for (int ni = 0; ni < 4; ++ni)
            b[ni] = *(const bf16x8*)&BsQ[(wc + ni * 16 + ro) * 32 + kof];
#pragma unroll
        for (int mi = 0; mi < 4; ++mi)
#pragma unroll
            for (int ni = 0; ni < 4; ++ni)
                acc[mi][ni] = __builtin_amdgcn_mfma_f32_16x16x32_bf16(a[mi], b[ni], acc[mi][ni], 0, 0, 0);
        pa = pn;
    }

    unsigned short* Cp = C + (long)z * NN * DO_;
#pragma unroll
    for (int mi = 0; mi < 4; ++mi)
#pragma unroll
        for (int ni = 0; ni < 4; ++ni) {
            const long col = wc + ni * 16 + (l & 15);
            const long rbase = row0 + wr + mi * 16 + ((l >> 4) << 2);
            f32x4 v = acc[mi][ni];
#pragma unroll
            for (int j = 0; j < 4; ++j) Cp[(rbase + j) * DO_ + col] = f2bf(v[j]);
        }
}

// ---- CSR gather D=256 ----
__device__ void dev_g256(int row, const float* __restrict__ h,
                         const int* __restrict__ rs, const int* __restrict__ csrc,
                         const float* __restrict__ norm, const float* __restrict__ bias,
                         unsigned short* __restrict__ outh, unsigned short* __restrict__ outl) {
    __shared__ int   sh_s[256];
    __shared__ float sh_ns[256];
    __shared__ float shred[4 * 256];
    const int tid = threadIdx.x, wv = tid >> 6, l = tid & 63;
    const int beg = rs[row], end = rs[row + 1];
    float4 acc = make_float4(0.f, 0.f, 0.f, 0.f);
    for (int base = beg; base < end; base += 256) {
        __syncthreads();
        if (base + tid < end) {
            int s = csrc[base + tid];
            sh_s[tid] = s;
            sh_ns[tid] = norm[s];
        }
        __syncthreads();
        int cnt = min(256, end - base);
        for (int j = wv; j < cnt; j += 4) {
            int s = sh_s[j];
            float ns = sh_ns[j];
            float4 hv = *(const float4*)&h[((long)s << 8) + (l << 2)];
            acc.x += hv.x * ns; acc.y += hv.y * ns; acc.z += hv.z * ns; acc.w += hv.w * ns;
        }
    }
    __syncthreads();
    *(float4*)&shred[wv * 256 + (l << 2)] = acc;
    __syncthreads();
    float val = shred[tid] + shred[256 + tid] + shred[512 + tid] + shred[768 + tid];
    float r = fmaxf(val * norm[row] + bias[tid], 0.f);
    unsigned short hb = f2bf(r);
    outh[((long)row << 8) + tid] = hb;
    outl[((long)row << 8) + tid] = f2bf(r - bf2f(hb));
}

// ---- CSR gather D=128 ----
__device__ void dev_g128(int row, const float* __restrict__ h,
                         const int* __restrict__ rs, const int* __restrict__ csrc,
                         const float* __restrict__ norm, const float* __restrict__ bias,
                         float* __restrict__ out) {
    __shared__ int   sh_s2[256];
    __shared__ float sh_ns2[256];
    __shared__ float shred2[4 * 128];
    const int tid = threadIdx.x, wv = tid >> 6, l = tid & 63;
    const int beg = rs[row], end = rs[row + 1];
    float2 acc = make_float2(0.f, 0.f);
    for (int base = beg; base < end; base += 256) {
        __syncthreads();
        if (base + tid < end) {
            int s = csrc[base + tid];
            sh_s2[tid] = s;
            sh_ns2[tid] = norm[s];
        }
        __syncthreads();
        int cnt = min(256, end - base);
        for (int j = wv; j < cnt; j += 4) {
            int s = sh_s2[j];
            float ns = sh_ns2[j];
            float2 hv = *(const float2*)&h[((long)s << 7) + (l << 1)];
            acc.x += hv.x * ns; acc.y += hv.y * ns;
        }
    }
    __syncthreads();
    *(float2*)&shred2[wv * 128 + (l << 1)] = acc;
    __syncthreads();
    if (tid < 128) {
        float val = shred2[tid] + shred2[128 + tid] + shred2[256 + tid] + shred2[384 + tid];
        float r = fmaxf(val * norm[row] + bias[tid], 0.f);
        out[((long)row << 7) + tid] = r;
    }
}

// ---- combine1: g2 = relu(sum_{z<16} part1 * (1/8192) + b1g) bf16 ----
__device__ void dev_c1(int idx, const unsigned short* __restrict__ part,
                       unsigned short* __restrict__ out, const float* __restrict__ bias) {
    int n4 = DH >> 2;
    if (idx >= NN * n4) return;
    int m = idx / n4, c = idx % n4;
    float4 s = make_float4(0.f, 0.f, 0.f, 0.f);
    for (int z = 0; z < 16; ++z) {
        u16x4 p = *(const u16x4*)&part[((long)z * NN + m) * DH + (c << 2)];
        s.x += bf2f(p.x); s.y += bf2f(p.y); s.z += bf2f(p.z); s.w += bf2f(p.w);
    }
    const float inv8192 = 1.0f / 8192.0f;
    float4 b = *(const float4*)&bias[c << 2];
    u16x4 o;
    o.x = f2bf(fmaxf(s.x * inv8192 + b.x, 0.f));
    o.y = f2bf(fmaxf(s.y * inv8192 + b.y, 0.f));
    o.z = f2bf(fmaxf(s.z * inv8192 + b.z, 0.f));
    o.w = f2bf(fmaxf(s.w * inv8192 + b.w, 0.f));
    *(u16x4*)&out[(long)m * DH + (c << 2)] = o;
}

// ---- eff transforms ----
__device__ void dev_eff_split(int idx, const float* __restrict__ w, const float* __restrict__ tao,
                              unsigned short* __restrict__ th, unsigned short* __restrict__ tl,
                              int I, int K0, int J) {
    if (idx >= I * J) return;
    int j = idx % J, i = idx / J;
    float s = 0.f;
    for (int k = 0; k < K0; ++k) s += w[i * K0 + k] * tao[k * J + j];
    unsigned short h = f2bf(s);
    th[j * I + i] = h;
    tl[j * I + i] = f2bf(s - bf2f(h));
}
__device__ void dev_eff_hi(int idx, const float* __restrict__ w, const float* __restrict__ tao,
                           unsigned short* __restrict__ th, int I, int K0, int J) {
    if (idx >= I * J) return;
    int j = idx % J, i = idx / J;
    float s = 0.f;
    for (int k = 0; k < K0; ++k) s += w[i * K0 + k] * tao[k * J + j];
    th[j * I + i] = f2bf(s);
}

// ---- CSR scan ----
__device__ void dev_scan256(const int* __restrict__ deg, int* __restrict__ rs, int* __restrict__ cur) {
    __shared__ int sums[256];
    int t = threadIdx.x;
    int loc[32];
    int s = 0;
#pragma unroll
    for (int j = 0; j < 32; ++j) { loc[j] = deg[t * 32 + j]; s += loc[j]; }
    sums[t] = s;
    __syncthreads();
    for (int off = 1; off < 256; off <<= 1) {
        int v = (t >= off) ? sums[t - off] : 0;
        __syncthreads();
        sums[t] += v;
        __syncthreads();
    }
    int base = (t > 0) ? sums[t - 1] : 0;
#pragma unroll
    for (int j = 0; j < 32; ++j) {
        rs[t * 32 + j] = base;
        cur[t * 32 + j] = base;
        base += loc[j];
    }
    if (t == 255) rs[NN] = base;
}

// ================= fused dispatch kernels =================

// S1: hist | eff1 | eff2 | eff3(hi) | eff4(hi)
__global__ __launch_bounds__(256) void k_s1(
    const int* __restrict__ dst, int* __restrict__ deg,
    const float* w1, const float* t1, unsigned short* e1h, unsigned short* e1l,
    const float* w2, const float* t2, unsigned short* e2h, unsigned short* e2l,
    const float* w3, const float* t3, unsigned short* e3h,
    const float* w4, const float* t4, unsigned short* e4h) {
    int b = blockIdx.x;
    if (b < 1024) {
        int e = b * 256 + threadIdx.x;
        atomicAdd(&deg[dst[e]], 1);
    } else if (b < 1536) {
        dev_eff_split((b - 1024) * 256 + threadIdx.x, w1, t1, e1h, e1l, DIN, DH, DH);
    } else if (b < 1664) {
        dev_eff_split((b - 1536) * 256 + threadIdx.x, w2, t2, e2h, e2l, DH, DO_, DO_);
    } else if (b < 2176) {
        dev_eff_hi((b - 1664) * 256 + threadIdx.x, w3, t3, e3h, DIN, DH, DH);
    } else {
        dev_eff_hi((b - 2176) * 256 + threadIdx.x, w4, t4, e4h, DH, DO_, DO_);
    }
}

// S2: LS1 (128) | GB1 (128) | scan (1) | PPMI u8 quantize (16384)
__global__ __launch_bounds__(256) void k_s2(
    const float* __restrict__ feats,
    const unsigned short* w1lh, const unsigned short* w1ll, float* h0,
    const unsigned short* w1gh, unsigned short* g0t,
    const int* deg, int* rs, int* cur,
    const float* __restrict__ PPMI, unsigned char* __restrict__ ppmi8) {
    int b = blockIdx.x;
    if (b < 128)      dev_ls1(b & 63, b >> 6, feats, w1lh, w1ll, h0);
    else if (b < 256) dev_gb1((b - 128) & 63, (b - 128) >> 6, feats, w1gh, g0t);
    else if (b == 256) dev_scan256(deg, rs, cur);
    else {
        long i = (long)(b - 257) * 256 + threadIdx.x;
        const float4* p = (const float4*)PPMI + i * 4;
        uint4 o;
        o.x = pack4_u8(p[0]);
        o.y = pack4_u8(p[1]);
        o.z = pack4_u8(p[2]);
        o.w = pack4_u8(p[3]);
        ((uint4*)ppmi8)[i] = o;
    }
}

// S3 (512 threads): P1 (64x16, u8 A) | fill
__global__ __launch_bounds__(512) void k_s3(
    const unsigned char* __restrict__ ppmi8, const unsigned short* g0t, unsigned short* part1,
    const int* __restrict__ src, const int* __restrict__ dst, int* cur, int* csrc) {
    int b = blockIdx.x;
    if (b < 1024) {
        dev_ppmi1(b & 63, b >> 6, ppmi8, g0t, part1);
    } else {
        int e = (b - 1024) * 512 + threadIdx.x;
        int pos = atomicAdd(&cur[dst[e]], 1);
        csrc[pos] = src[e];
    }
}

// S4: gather256 (8192) | combine1 (2048)
__global__ __launch_bounds__(256) void k_s4(
    const float* h0, const int* rs, const int* csrc, const float* norm, const float* b1,
    unsigned short* h1h, unsigned short* h1l,
    const unsigned short* part1, unsigned short* g2, const float* b1g) {
    int b = blockIdx.x;
    if (b < 8192) dev_g256(b, h0, rs, csrc, norm, b1, h1h, h1l);
    else          dev_c1((b - 8192) * 256 + threadIdx.x, part1, g2, b1g);
}

// S5: LS2 (64) | GB2 (64)
__global__ __launch_bounds__(256) void k_s5(
    const unsigned short* h1h, const unsigned short* h1l,
    const unsigned short* w2lh, const unsigned short* w2ll, float* h2,
    const unsigned short* g2, const unsigned short* w2gh, unsigned short* g3t) {
    int b = blockIdx.x;
    if (b < 64) dev_gemm_split(b, 0, h1h, h1l, w2lh, w2ll, h2, NN, DO_, DH);
    else        dev_gemm_b1(b - 64, 0, g2, w2gh, g3t, NN, DO_, DH);
}

// S6: P2 (64x8, u8 A) | gather128 (8192)
__global__ __launch_bounds__(256) void k_s6(
    const unsigned char* __restrict__ ppmi8, const unsigned short* g3t, unsigned short* part2,
    const float* h2, const int* rs, const int* csrc, const float* norm, const float* b2,
    float* HL) {
    int b = blockIdx.x;
    if (b < 512) dev_ppmi2(b & 63, b >> 6, ppmi8, g3t, part2);
    else         dev_g128(b - 512, h2, rs, csrc, norm, b2, HL);
}

// S7: attn + fused combine2 (part2 carries x8192 scale -> remove before bias)
__global__ __launch_bounds__(256) void k_s7(
    const float* __restrict__ HL, const unsigned short* __restrict__ part2,
    const float* __restrict__ b2g,
    const float* __restrict__ Wa, const float* __restrict__ Wc,
    const float* __restrict__ bc, float* __restrict__ out) {
    int wv = threadIdx.x >> 6, l = threadIdx.x & 63;
    int row = blockIdx.x * 4 + wv;
    float2 hg = make_float2(0.f, 0.f);
#pragma unroll
    for (int z = 0; z < 8; ++z) {
        unsigned int u = *(const unsigned int*)&part2[((long)z * NN + row) * DO_ + 2 * l];
        hg.x += bf2f((unsigned short)(u & 0xffffu));
        hg.y += bf2f((unsigned short)(u >> 16));
    }
    const float inv8192 = 1.0f / 8192.0f;
    float2 bg = *(const float2*)&b2g[2 * l];
    hg.x = fmaxf(hg.x * inv8192 + bg.x, 0.f);
    hg.y = fmaxf(hg.y * inv8192 + bg.y, 0.f);

    float2 hl = *(const float2*)&HL[(long)row * DO_ + l * 2];
    float4 wa0 = *(const float4*)&Wa[(2 * l) * 2];
    float4 wa1 = *(const float4*)&Wa[(DO_ + 2 * l) * 2];
    float p0 = hl.x * wa0.x + hl.y * wa0.z + hg.x * wa1.x + hg.y * wa1.z;
    float p1 = hl.x * wa0.y + hl.y * wa0.w + hg.x * wa1.y + hg.y * wa1.w;
#pragma unroll
    for (int off = 32; off >= 1; off >>= 1) {
        p0 += __shfl_xor(p0, off);
        p1 += __shfl_xor(p1, off);
    }
    float mx = fmaxf(p0, p1);
    float e0 = __expf(p0 - mx), e1 = __expf(p1 - mx);
    float inv = 1.f / (e0 + e1);
    float a0 = e0 * inv, a1 = e1 * inv;
    float z0 = a0 * hl.x + a1 * hg.x;
    float z1 = a0 * hl.y + a1 * hg.y;
    float4 wcA0 = *(const float4*)&Wc[(2 * l) * NCLS];
    float4 wcA1 = *(const float4*)&Wc[(2 * l) * NCLS + 4];
    float4 wcB0 = *(const float4*)&Wc[(2 * l + 1) * NCLS];
    float4 wcB1 = *(const float4*)&Wc[(2 * l + 1) * NCLS + 4];
    float q0 = z0 * wcA0.x + z1 * wcB0.x;
    float q1 = z0 * wcA0.y + z1 * wcB0.y;
    float q2 = z0 * wcA0.z + z1 * wcB0.z;
    float q3 = z0 * wcA0.w + z1 * wcB0.w;
    float q4 = z0 * wcA1.x + z1 * wcB1.x;
    float q5 = z0 * wcA1.y + z1 * wcB1.y;
    float q6 = z0 * wcA1.z + z1 * wcB1.z;
    float q7 = z0 * wcA1.w + z1 * wcB1.w;
#pragma unroll
    for (int off = 32; off >= 1; off >>= 1) {
        q0 += __shfl_xor(q0, off); q1 += __shfl_xor(q1, off);
        q2 += __shfl_xor(q2, off); q3 += __shfl_xor(q3, off);
        q4 += __shfl_xor(q4, off); q5 += __shfl_xor(q5, off);
        q6 += __shfl_xor(q6, off); q7 += __shfl_xor(q7, off);
    }
    if (l == 0) {
        float* o = &out[(long)row * NCLS];
        o[0] = q0 + bc[0]; o[1] = q1 + bc[1]; o[2] = q2 + bc[2]; o[3] = q3 + bc[3];
        o[4] = q4 + bc[4]; o[5] = q5 + bc[5]; o[6] = q6 + bc[6]; o[7] = q7 + bc[7];
    }
}

extern "C" void kernel_launch(void* const* d_in, const int* in_sizes, int n_in,
                              void* d_out, int out_size, void* d_ws, size_t ws_size,
                              hipStream_t stream) {
    (void)in_sizes; (void)n_in; (void)out_size; (void)ws_size;
    const float* feats = (const float*)d_in[0];
    const float* norm  = (const float*)d_in[1];
    const float* tao1L = (const float*)d_in[2];
    const float* tao2L = (const float*)d_in[3];
    const float* tao1G = (const float*)d_in[4];
    const float* tao2G = (const float*)d_in[5];
    const float* PPMI  = (const float*)d_in[6];
    const float* w1  = (const float*)d_in[7];
    const float* b1  = (const float*)d_in[8];
    const float* w2  = (const float*)d_in[9];
    const float* b2  = (const float*)d_in[10];
    const float* w1g = (const float*)d_in[11];
    const float* b1g = (const float*)d_in[12];
    const float* w2g = (const float*)d_in[13];
    const float* b2g = (const float*)d_in[14];
    const float* Wa  = (const float*)d_in[15];
    const float* Wc  = (const float*)d_in[16];
    const float* bc  = (const float*)d_in[17];
    const int* src = (const int*)d_in[18];
    const int* dst = (const int*)d_in[19];

    char* ws = (char*)d_ws;
    size_t off = 0;
    auto alloc = [&](size_t b) { void* p = (void*)(ws + off); off += (b + 255) & ~(size_t)255; return p; };
    unsigned short* w1lh = (unsigned short*)alloc((size_t)DH * DIN * 2);
    unsigned short* w1ll = (unsigned short*)alloc((size_t)DH * DIN * 2);
    unsigned short* w2lh = (unsigned short*)alloc((size_t)DO_ * DH * 2);
    unsigned short* w2ll = (unsigned short*)alloc((size_t)DO_ * DH * 2);
    unsigned short* w1gh = (unsigned short*)alloc((size_t)DH * DIN * 2);
    unsigned short* w2gh = (unsigned short*)alloc((size_t)DO_ * DH * 2);
    unsigned short* g0t = (unsigned short*)alloc((size_t)DH * NN * 2);
    unsigned short* g2  = (unsigned short*)alloc((size_t)NN * DH * 2);
    unsigned short* g3t = (unsigned short*)alloc((size_t)DO_ * NN * 2);
    unsigned short* h1h = (unsigned short*)alloc((size_t)NN * DH * 2);
    unsigned short* h1l = (unsigned short*)alloc((size_t)NN * DH * 2);
    float* h0 = (float*)alloc((size_t)NN * DH * 4);
    float* h2 = (float*)alloc((size_t)NN * DO_ * 4);
    float* HL = (float*)alloc((size_t)NN * DO_ * 4);
    unsigned short* part1 = (unsigned short*)alloc((size_t)16 * NN * DH * 2);  // 67 MB
    unsigned short* part2 = (unsigned short*)alloc((size_t)8 * NN * DO_ * 2);  // 16.8 MB
    unsigned char* ppmi8 = (unsigned char*)alloc((size_t)NN * NN);             // 67 MB
    int* deg  = (int*)alloc((size_t)NN * 4);
    int* rs   = (int*)alloc((size_t)(NN + 1) * 4);
    int* cur  = (int*)alloc((size_t)NN * 4);
    int* csrc = (int*)alloc((size_t)NE * 4);

    hipMemsetAsync(deg, 0, (size_t)NN * 4, stream);

    // S1: hist | eff transforms
    k_s1<<<dim3(2304), dim3(256), 0, stream>>>(
        dst, deg,
        w1,  tao1L, w1lh, w1ll,
        w2,  tao2L, w2lh, w2ll,
        w1g, tao1G, w1gh,
        w2g, tao2G, w2gh);

    // S2: LS1 | GB1 | scan | PPMI->u8 quantize
    k_s2<<<dim3(16641), dim3(256), 0, stream>>>(feats, w1lh, w1ll, h0, w1gh, g0t,
                                                deg, rs, cur, PPMI, ppmi8);

    // S3: P1 (z=16, u8 A, swizzled LDS) | fill
    k_s3<<<dim3(1536), dim3(512), 0, stream>>>(ppmi8, g0t, part1, src, dst, cur, csrc);

    // S4: gather256 | combine1 (Z=16, removes x8192 scale)
    k_s4<<<dim3(10240), dim3(256), 0, stream>>>(h0, rs, csrc, norm, b1, h1h, h1l, part1, g2, b1g);

    // S5: LS2 | GB2
    k_s5<<<dim3(128), dim3(256), 0, stream>>>(h1h, h1l, w2lh, w2ll, h2, g2, w2gh, g3t);

    // S6: P2 (u8 A, swizzled LDS) | gather128
    k_s6<<<dim3(8704), dim3(256), 0, stream>>>(ppmi8, g3t, part2, h2, rs, csrc, norm, b2, HL);

    // S7: attn + fused combine2 (removes x8192 scale)
    k_s7<<<dim3(2048), dim3(256), 0, stream>>>(HL, part2, b2g, Wa, Wc, bc, (float*)d_out);
}